// Round 1
// baseline (75.030 us; speedup 1.0000x reference)
//
#include <hip/hip_runtime.h>
#include <hip/hip_bf16.h>
#include <cstdint>
#include <cstddef>

typedef __attribute__((ext_vector_type(8))) short bf16x8;
typedef __attribute__((ext_vector_type(16))) float f32x16;

__device__ __forceinline__ unsigned short f2bf(float f) {
  union { float f; unsigned u; } v; v.f = f;
  unsigned r = v.u + 0x7FFFu + ((v.u >> 16) & 1u);
  return (unsigned short)(r >> 16);
}

// ---------------------------------------------------------------------------
// K0: W [1024][1000] f32 (row-major, k-major) -> Wt [1024 cls][1024 k] bf16,
// classes >= 1000 zero-padded. Tiled transpose through LDS.
// ---------------------------------------------------------------------------
__global__ __launch_bounds__(256) void k0_wt(const float* __restrict__ W,
                                             unsigned short* __restrict__ Wt) {
  __shared__ float tile[64][65];
  int k0 = (blockIdx.x & 15) * 64;
  int c0 = (blockIdx.x >> 4) * 64;
  int tx = threadIdx.x & 63;
  int ty = threadIdx.x >> 6;  // 0..3
#pragma unroll
  for (int i = 0; i < 16; ++i) {
    int r = i * 4 + ty;  // k within tile
    int c = c0 + tx;
    tile[r][tx] = (c < 1000) ? W[(size_t)(k0 + r) * 1000 + c] : 0.f;
  }
  __syncthreads();
#pragma unroll
  for (int i = 0; i < 16; ++i) {
    int ct = i * 4 + ty;  // cls within tile
    float v = tile[tx][ct];
    Wt[(size_t)(c0 + ct) * 1024 + (k0 + tx)] = f2bf(v);
  }
}

// ---------------------------------------------------------------------------
// K1: per-row 1/max(||x||,eps) -> rnorm, x -> bf16 copy, s += x_row * rnorm
// (block pre-reduced, then global atomics). 512 blocks x 256 thr, 16 rows/blk.
// ---------------------------------------------------------------------------
__global__ __launch_bounds__(256) void k1_norm(const float* __restrict__ x,
                                               unsigned short* __restrict__ xbf,
                                               float* __restrict__ rnorm,
                                               float* __restrict__ s) {
  __shared__ float sblk[4][1024];
  int tid = threadIdx.x;
  int wid = tid >> 6, lane = tid & 63;
  float4 sacc[4];
#pragma unroll
  for (int j = 0; j < 4; ++j) sacc[j] = make_float4(0.f, 0.f, 0.f, 0.f);

#pragma unroll
  for (int r = 0; r < 4; ++r) {
    int row = blockIdx.x * 16 + wid * 4 + r;
    const float4* xr = (const float4*)(x + (size_t)row * 1024);
    float4 v[4];
    float ss = 0.f;
#pragma unroll
    for (int j = 0; j < 4; ++j) {
      v[j] = xr[lane + j * 64];
      ss += v[j].x * v[j].x + v[j].y * v[j].y + v[j].z * v[j].z + v[j].w * v[j].w;
    }
#pragma unroll
    for (int m = 1; m < 64; m <<= 1) ss += __shfl_xor(ss, m);
    float rn = 1.f / fmaxf(sqrtf(ss), 1e-8f);
    if (lane == 0) rnorm[row] = rn;
#pragma unroll
    for (int j = 0; j < 4; ++j) {
      ushort4 hv;
      hv.x = f2bf(v[j].x); hv.y = f2bf(v[j].y);
      hv.z = f2bf(v[j].z); hv.w = f2bf(v[j].w);
      ((ushort4*)(xbf + (size_t)row * 1024))[lane + j * 64] = hv;
      sacc[j].x += v[j].x * rn; sacc[j].y += v[j].y * rn;
      sacc[j].z += v[j].z * rn; sacc[j].w += v[j].w * rn;
    }
  }
#pragma unroll
  for (int j = 0; j < 4; ++j) ((float4*)sblk[wid])[j * 64 + lane] = sacc[j];
  __syncthreads();
  for (int d = tid; d < 1024; d += 256) {
    float t = sblk[0][d] + sblk[1][d] + sblk[2][d] + sblk[3][d];
    atomicAdd(&s[d], t);
  }
}

// ---------------------------------------------------------------------------
// K3: bf16 MFMA GEMM (classes x rows) fused with per-chunk softmax stats.
// Grid 256 = 64 row-blocks (BM=128) x 4 class-chunks (BC=256). 4 waves:
// wave (cw,rw) owns 128 classes x 64 rows = mf4 x nf2 of 32x32x16 frags.
// Writes per-(chunk,row) partial (m, Z=sum e^{l-m}, S=sum e^{l-m}(l-m)).
// Bias folded into accumulator init; classes >= 1000 init to -1e30 (masked).
// ---------------------------------------------------------------------------
#define BM 128
#define BC 256
#define BK 64

__global__ __launch_bounds__(256, 1) void k3_gemm(const unsigned short* __restrict__ xbf,
                                                  const unsigned short* __restrict__ wt,
                                                  const float* __restrict__ bias,
                                                  float* __restrict__ pm,
                                                  float* __restrict__ pz,
                                                  float* __restrict__ ps) {
  // LDS: x dbuf 2x16KB @0, w dbuf 2x32KB @32768. Merge arrays alias lw after loop.
  __shared__ __align__(16) char lds[98304];

  int tid = threadIdx.x;
  int lane = tid & 63;
  int wid = tid >> 6;
  int cw = wid & 1;   // class-wave (0..1)
  int rw = wid >> 1;  // row-wave (0..1)
  int hi = lane >> 5;
  int l31 = lane & 31;

  int rb = blockIdx.x & 63;
  int chunk = blockIdx.x >> 6;
  int R0 = rb * BM;
  int C0 = chunk * BC;

  f32x16 acc[4][2];
#pragma unroll
  for (int mf = 0; mf < 4; ++mf) {
#pragma unroll
    for (int q = 0; q < 16; ++q) {
      int cls_g = C0 + cw * 128 + mf * 32 + (q & 3) + 8 * (q >> 2) + 4 * hi;
      float bv = (cls_g < 1000) ? bias[cls_g] : -1e30f;
      acc[mf][0][q] = bv;
      acc[mf][1][q] = bv;
    }
  }

  const char* gx = (const char*)(xbf + (size_t)R0 * 1024);
  const char* gw = (const char*)(wt + (size_t)C0 * 1024);

  auto stage = [&](int step, int b) {
    const char* gxs = gx + step * (BK * 2);
    char* lxb = lds + b * 16384;
#pragma unroll
    for (int i = 0; i < 4; ++i) {
      int ci = i * 256 + tid;
      int row = ci >> 3;
      int kb = (ci & 7) << 4;
      uint4 v = *(const uint4*)(gxs + (size_t)row * 2048 + kb);
      *(uint4*)(lxb + row * 128 + (kb ^ ((row & 7) << 4))) = v;
    }
    const char* gws = gw + step * (BK * 2);
    char* lwb = lds + 32768 + b * 32768;
#pragma unroll
    for (int i = 0; i < 8; ++i) {
      int ci = i * 256 + tid;
      int cls = ci >> 3;
      int kb = (ci & 7) << 4;
      uint4 v = *(const uint4*)(gws + (size_t)cls * 2048 + kb);
      *(uint4*)(lwb + cls * 128 + (kb ^ ((cls & 7) << 4))) = v;
    }
  };

  stage(0, 0);
  __syncthreads();
  for (int it = 0; it < 16; ++it) {
    int cur = it & 1;
    if (it < 15) stage(it + 1, cur ^ 1);
    const char* lxb = lds + cur * 16384;
    const char* lwb = lds + 32768 + cur * 32768;
#pragma unroll
    for (int ksub = 0; ksub < 4; ++ksub) {
      int kb = ksub * 32 + hi * 16;
      bf16x8 a[4], bfr[2];
#pragma unroll
      for (int mf = 0; mf < 4; ++mf) {
        int cls = cw * 128 + mf * 32 + l31;
        a[mf] = *(const bf16x8*)(lwb + cls * 128 + (kb ^ ((cls & 7) << 4)));
      }
#pragma unroll
      for (int nf = 0; nf < 2; ++nf) {
        int row = rw * 64 + nf * 32 + l31;
        bfr[nf] = *(const bf16x8*)(lxb + row * 128 + (kb ^ ((row & 7) << 4)));
      }
#pragma unroll
      for (int mf = 0; mf < 4; ++mf)
#pragma unroll
        for (int nf = 0; nf < 2; ++nf)
          acc[mf][nf] = __builtin_amdgcn_mfma_f32_32x32x16_bf16(a[mf], bfr[nf],
                                                                acc[mf][nf], 0, 0, 0);
    }
    __syncthreads();
  }

  // Epilogue: per-row softmax stats over this wave's 128 classes, then merge
  // the two class-waves in LDS (aliases lw region; safe after final barrier).
  float* mm = (float*)(lds + 32768);
  float* zz = (float*)(lds + 32768 + 1024);
  float* sv = (float*)(lds + 32768 + 2048);
#pragma unroll
  for (int nf = 0; nf < 2; ++nf) {
    float m1 = -1e30f;
#pragma unroll
    for (int mf = 0; mf < 4; ++mf)
#pragma unroll
      for (int q = 0; q < 16; ++q) m1 = fmaxf(m1, acc[mf][nf][q]);
    float m = fmaxf(m1, __shfl_xor(m1, 32));
    float z1 = 0.f, s1 = 0.f;
#pragma unroll
    for (int mf = 0; mf < 4; ++mf)
#pragma unroll
      for (int q = 0; q < 16; ++q) {
        float t = acc[mf][nf][q] - m;
        float e = expf(t);
        z1 += e;
        s1 += e * t;
      }
    float z = z1 + __shfl_xor(z1, 32);
    float sb = s1 + __shfl_xor(s1, 32);
    if (lane < 32) {
      int rl = rw * 64 + nf * 32 + l31;
      mm[cw * 128 + rl] = m;
      zz[cw * 128 + rl] = z;
      sv[cw * 128 + rl] = sb;
    }
  }
  __syncthreads();
  if (tid < 128) {
    float m0 = mm[tid], mA = mm[128 + tid];
    float z0 = zz[tid], zA = zz[128 + tid];
    float s0 = sv[tid], sA = sv[128 + tid];
    float M = fmaxf(m0, mA);
    float e0 = expf(m0 - M), e1 = expf(mA - M);
    float Z = z0 * e0 + zA * e1;
    float S = e0 * (s0 + (m0 - M) * z0) + e1 * (sA + (mA - M) * zA);
    size_t o = (size_t)chunk * 8192 + R0 + tid;
    pm[o] = M;
    pz[o] = Z;
    ps[o] = S;
  }
}

// ---------------------------------------------------------------------------
// K4: merge 4 chunk-partials per row -> loss; weight = dot(x_row, s)*rnorm/B
// (f32 for precision); out = loss * weight. One wave per row.
// ---------------------------------------------------------------------------
__global__ __launch_bounds__(256) void k4_final(const float* __restrict__ x,
                                                const float* __restrict__ s,
                                                const float* __restrict__ rnorm,
                                                const float* __restrict__ pm,
                                                const float* __restrict__ pz,
                                                const float* __restrict__ ps,
                                                float* __restrict__ out) {
  int tid = threadIdx.x;
  int wid = tid >> 6, lane = tid & 63;
  int row = blockIdx.x * 4 + wid;
  const float4* xr = (const float4*)(x + (size_t)row * 1024);
  const float4* s4 = (const float4*)s;
  float dot = 0.f;
#pragma unroll
  for (int j = 0; j < 4; ++j) {
    float4 a = xr[lane + j * 64];
    float4 b = s4[lane + j * 64];
    dot += a.x * b.x + a.y * b.y + a.z * b.z + a.w * b.w;
  }
#pragma unroll
  for (int m = 1; m < 64; m <<= 1) dot += __shfl_xor(dot, m);
  if (lane == 0) {
    float mv[4], zv[4], svv[4];
    float M = -1e30f;
#pragma unroll
    for (int c = 0; c < 4; ++c) {
      mv[c] = pm[(size_t)c * 8192 + row];
      zv[c] = pz[(size_t)c * 8192 + row];
      svv[c] = ps[(size_t)c * 8192 + row];
      M = fmaxf(M, mv[c]);
    }
    float Z = 0.f, S = 0.f;
#pragma unroll
    for (int c = 0; c < 4; ++c) {
      float e = expf(mv[c] - M);
      Z += zv[c] * e;
      S += e * (svv[c] + (mv[c] - M) * zv[c]);
    }
    float loss = S / Z - logf(Z);
    float w = dot * rnorm[row] * (1.f / 8192.f);
    out[row] = loss * w;
  }
}

// ---------------------------------------------------------------------------
extern "C" void kernel_launch(void* const* d_in, const int* in_sizes, int n_in,
                              void* d_out, int out_size, void* d_ws, size_t ws_size,
                              hipStream_t stream) {
  (void)in_sizes; (void)n_in; (void)out_size; (void)ws_size;
  const float* x = (const float*)d_in[0];
  const float* W = (const float*)d_in[1];
  const float* b = (const float*)d_in[2];
  float* out = (float*)d_out;
  char* ws = (char*)d_ws;

  // ws layout (bytes):
  unsigned short* Wt = (unsigned short*)(ws + 0);           // 1024*1024*2 = 2 MiB
  unsigned short* xbf = (unsigned short*)(ws + 2097152);    // 8192*1024*2 = 16 MiB
  float* rnorm = (float*)(ws + 18874368);                   // 32 KiB
  float* s = (float*)(ws + 18907136);                       // 4 KiB
  float* pm = (float*)(ws + 18911232);                      // 4*8192*4 = 128 KiB
  float* pz = (float*)(ws + 18911232 + 131072);
  float* ps = (float*)(ws + 18911232 + 262144);

  hipMemsetAsync(s, 0, 4096, stream);
  k0_wt<<<256, 256, 0, stream>>>(W, Wt);
  k1_norm<<<512, 256, 0, stream>>>(x, xbf, rnorm, s);
  k3_gemm<<<256, 256, 0, stream>>>(xbf, Wt, b, pm, pz, ps);
  k4_final<<<2048, 256, 0, stream>>>(x, s, rnorm, pm, pz, ps, out);
}

// Round 2
// 67.372 us; speedup vs baseline: 1.1137x; 1.1137x over previous
//
#include <hip/hip_runtime.h>
#include <hip/hip_bf16.h>
#include <cstdint>
#include <cstddef>

typedef __attribute__((ext_vector_type(8))) short bf16x8;
typedef __attribute__((ext_vector_type(4))) float f32x4;

__device__ __forceinline__ unsigned short f2bf(float f) {
  union { float f; unsigned u; } v; v.f = f;
  unsigned r = v.u + 0x7FFFu + ((v.u >> 16) & 1u);
  return (unsigned short)(r >> 16);
}

__device__ __forceinline__ float bf2f(unsigned short h) {
  union { float f; unsigned u; } c; c.u = ((unsigned)h) << 16;
  return c.f;
}

__device__ __forceinline__ void gload_lds16(const void* g, void* l) {
  __builtin_amdgcn_global_load_lds(
      (const __attribute__((address_space(1))) unsigned int*)g,
      (__attribute__((address_space(3))) unsigned int*)l, 16, 0, 0);
}

// ---------------------------------------------------------------------------
// K01 fused: blocks [0,256): W transpose->bf16 Wt[1024cls][1024k] (pad 0).
//            blocks [256,768): per-row rnorm, x->bf16, s += xn (atomics).
// ---------------------------------------------------------------------------
__global__ __launch_bounds__(256) void k01_prep(const float* __restrict__ W,
                                                unsigned short* __restrict__ Wt,
                                                const float* __restrict__ x,
                                                unsigned short* __restrict__ xbf,
                                                float* __restrict__ rnorm,
                                                float* __restrict__ s) {
  __shared__ __align__(16) char sm[16640];
  int tid = threadIdx.x;
  if (blockIdx.x < 256) {
    float (*tile)[65] = (float(*)[65])sm;
    int k0 = (blockIdx.x & 15) * 64;
    int c0 = (blockIdx.x >> 4) * 64;
    int tx = tid & 63;
    int ty = tid >> 6;
#pragma unroll
    for (int i = 0; i < 16; ++i) {
      int r = i * 4 + ty;
      int c = c0 + tx;
      tile[r][tx] = (c < 1000) ? W[(size_t)(k0 + r) * 1000 + c] : 0.f;
    }
    __syncthreads();
#pragma unroll
    for (int i = 0; i < 16; ++i) {
      int ct = i * 4 + ty;
      Wt[(size_t)(c0 + ct) * 1024 + (k0 + tx)] = f2bf(tile[tx][ct]);
    }
    return;
  }
  // ---- norm part ----
  float (*sblk)[1024] = (float(*)[1024])sm;  // only 4 rows used via wid
  int bid = blockIdx.x - 256;
  int wid = tid >> 6, lane = tid & 63;
  float4 sacc[4];
#pragma unroll
  for (int j = 0; j < 4; ++j) sacc[j] = make_float4(0.f, 0.f, 0.f, 0.f);
#pragma unroll
  for (int r = 0; r < 4; ++r) {
    int row = bid * 16 + wid * 4 + r;
    const float4* xr = (const float4*)(x + (size_t)row * 1024);
    float4 v[4];
    float ss = 0.f;
#pragma unroll
    for (int j = 0; j < 4; ++j) {
      v[j] = xr[lane + j * 64];
      ss += v[j].x * v[j].x + v[j].y * v[j].y + v[j].z * v[j].z + v[j].w * v[j].w;
    }
#pragma unroll
    for (int m = 1; m < 64; m <<= 1) ss += __shfl_xor(ss, m);
    float rn = 1.f / fmaxf(sqrtf(ss), 1e-8f);
    if (lane == 0) rnorm[row] = rn;
#pragma unroll
    for (int j = 0; j < 4; ++j) {
      ushort4 hv;
      hv.x = f2bf(v[j].x); hv.y = f2bf(v[j].y);
      hv.z = f2bf(v[j].z); hv.w = f2bf(v[j].w);
      ((ushort4*)(xbf + (size_t)row * 1024))[lane + j * 64] = hv;
      sacc[j].x += v[j].x * rn; sacc[j].y += v[j].y * rn;
      sacc[j].z += v[j].z * rn; sacc[j].w += v[j].w * rn;
    }
  }
#pragma unroll
  for (int j = 0; j < 4; ++j) ((float4*)sblk[wid])[j * 64 + lane] = sacc[j];
  __syncthreads();
  for (int d = tid; d < 1024; d += 256) {
    float t = sblk[0][d] + sblk[1][d] + sblk[2][d] + sblk[3][d];
    atomicAdd(&s[d], t);
  }
}

// ---------------------------------------------------------------------------
// K3: bf16 MFMA GEMM (cls x rows), m97 structure: 128x128 tile, BK=64,
// global_load_lds width-16 (linear LDS both sides, no swizzle), T3 minimum
// 2-phase dbuf, 1 barrier per K-step. Grid 512 = 8 cls-chunks x 64 row-blocks
// -> 2 blocks/CU. 4 waves: wave(wm,wn) = 64cls x 64row of 16x16x32 frags.
// Fused epilogue: per-(chunk,row) softmax partials (m, Z, S).
// ---------------------------------------------------------------------------
__global__ __launch_bounds__(256) void k3_gemm(const unsigned short* __restrict__ xbf,
                                               const unsigned short* __restrict__ wt,
                                               const float* __restrict__ bias,
                                               float* __restrict__ pm,
                                               float* __restrict__ pz,
                                               float* __restrict__ ps) {
  // dbuf: buf b at b*32768: A(Wt tile) 16KB, B(x tile) 16KB.
  __shared__ __align__(16) char lds[65536];

  int tid = threadIdx.x;
  int lane = tid & 63;
  int wid = tid >> 6;
  int wm = wid & 1;   // cls half
  int wn = wid >> 1;  // row half
  int rb = blockIdx.x & 63;
  int cb = blockIdx.x >> 6;
  int R0 = rb * 128;
  int C0 = cb * 128;

  // bias (+mask for padded cls >= 1000) folded into accumulator init.
  // 16x16 C/D map: row(cls) = (lane>>4)*4 + q, col(xrow) = lane&15.
  float bv[4][4];
#pragma unroll
  for (int mf = 0; mf < 4; ++mf)
#pragma unroll
    for (int q = 0; q < 4; ++q) {
      int cls_g = C0 + wm * 64 + mf * 16 + (lane >> 4) * 4 + q;
      bv[mf][q] = (cls_g < 1000) ? bias[cls_g] : -1e30f;
    }
  f32x4 acc[4][4];
#pragma unroll
  for (int mf = 0; mf < 4; ++mf)
#pragma unroll
    for (int nf = 0; nf < 4; ++nf)
#pragma unroll
      for (int q = 0; q < 4; ++q) acc[mf][nf][q] = bv[mf][q];

  const char* gA = (const char*)(wt + (size_t)C0 * 1024);
  const char* gB = (const char*)(xbf + (size_t)R0 * 1024);
  int goff = (lane >> 3) * 2048 + (lane & 7) * 16;  // row-in-chunk, k-byte

  // stage one K-step tile pair into buf b (async, linear LDS).
  // 16 chunks of 1KB per matrix; wave w issues chunks w*4..w*4+3.
  auto stage = [&](int step, int b) {
    char* lA = lds + b * 32768;
    char* lB = lA + 16384;
    const char* gAs = gA + step * 128 + goff;
    const char* gBs = gB + step * 128 + goff;
#pragma unroll
    for (int i = 0; i < 4; ++i) {
      int c = wid * 4 + i;
      gload_lds16(gAs + c * 16384, lA + c * 1024);
      gload_lds16(gBs + c * 16384, lB + c * 1024);
    }
  };

  stage(0, 0);
  __syncthreads();
  int cur = 0;
  int rfa = wm * 64 + (lane & 15);
  int rfb = wn * 64 + (lane & 15);
  for (int t = 0; t < 16; ++t) {
    if (t < 15) stage(t + 1, cur ^ 1);
    const char* A = lds + cur * 32768;
    const char* B = A + 16384;
#pragma unroll
    for (int ksub = 0; ksub < 2; ++ksub) {
      int kb = ksub * 64 + (lane >> 4) * 16;
      bf16x8 a[4], bb[4];
#pragma unroll
      for (int mf = 0; mf < 4; ++mf)
        a[mf] = *(const bf16x8*)(A + (rfa + mf * 16) * 128 + kb);
#pragma unroll
      for (int nf = 0; nf < 4; ++nf)
        bb[nf] = *(const bf16x8*)(B + (rfb + nf * 16) * 128 + kb);
#pragma unroll
      for (int mf = 0; mf < 4; ++mf)
#pragma unroll
        for (int nf = 0; nf < 4; ++nf)
          acc[mf][nf] = __builtin_amdgcn_mfma_f32_16x16x32_bf16(a[mf], bb[nf],
                                                                acc[mf][nf], 0, 0, 0);
    }
    __syncthreads();
    cur ^= 1;
  }

  // Epilogue: per x-row stats over this wave's 64 cls, merge wm halves in LDS.
  float* mm = (float*)lds;
  float* zz = (float*)(lds + 1024);
  float* sv = (float*)(lds + 2048);
#pragma unroll
  for (int nf = 0; nf < 4; ++nf) {
    float m1 = -1e30f;
#pragma unroll
    for (int mf = 0; mf < 4; ++mf)
#pragma unroll
      for (int q = 0; q < 4; ++q) m1 = fmaxf(m1, acc[mf][nf][q]);
    m1 = fmaxf(m1, __shfl_xor(m1, 16));
    m1 = fmaxf(m1, __shfl_xor(m1, 32));
    float z1 = 0.f, s1 = 0.f;
#pragma unroll
    for (int mf = 0; mf < 4; ++mf)
#pragma unroll
      for (int q = 0; q < 4; ++q) {
        float tt = acc[mf][nf][q] - m1;
        float e = expf(tt);
        z1 += e;
        s1 += e * tt;
      }
    z1 += __shfl_xor(z1, 16); z1 += __shfl_xor(z1, 32);
    s1 += __shfl_xor(s1, 16); s1 += __shfl_xor(s1, 32);
    if (lane < 16) {
      int r = wn * 64 + nf * 16 + lane;
      mm[wm * 128 + r] = m1;
      zz[wm * 128 + r] = z1;
      sv[wm * 128 + r] = s1;
    }
  }
  __syncthreads();
  if (tid < 128) {
    float m0 = mm[tid], mA = mm[128 + tid];
    float z0 = zz[tid], zA = zz[128 + tid];
    float s0 = sv[tid], sA = sv[128 + tid];
    float M = fmaxf(m0, mA);
    float e0 = expf(m0 - M), e1 = expf(mA - M);
    float Z = z0 * e0 + zA * e1;
    float S = e0 * (s0 + (m0 - M) * z0) + e1 * (sA + (mA - M) * zA);
    size_t o = (size_t)cb * 8192 + R0 + tid;
    pm[o] = M;
    pz[o] = Z;
    ps[o] = S;
  }
}

// ---------------------------------------------------------------------------
// K4: merge 8 chunk-partials -> loss; weight = dot(xbf_row, s)*rnorm/B.
// One wave per row; xbf (not x) halves the read.
// ---------------------------------------------------------------------------
__global__ __launch_bounds__(256) void k4_final(const unsigned short* __restrict__ xbf,
                                                const float* __restrict__ s,
                                                const float* __restrict__ rnorm,
                                                const float* __restrict__ pm,
                                                const float* __restrict__ pz,
                                                const float* __restrict__ ps,
                                                float* __restrict__ out) {
  int tid = threadIdx.x;
  int wid = tid >> 6, lane = tid & 63;
  int row = blockIdx.x * 4 + wid;
  const bf16x8* xr = (const bf16x8*)(xbf + (size_t)row * 1024);
  const float4* s4 = (const float4*)s;
  float dot = 0.f;
#pragma unroll
  for (int j = 0; j < 2; ++j) {
    bf16x8 v = xr[lane + j * 64];
    float4 sa = s4[(lane + j * 64) * 2];
    float4 sb = s4[(lane + j * 64) * 2 + 1];
    dot += bf2f((unsigned short)v[0]) * sa.x + bf2f((unsigned short)v[1]) * sa.y +
           bf2f((unsigned short)v[2]) * sa.z + bf2f((unsigned short)v[3]) * sa.w +
           bf2f((unsigned short)v[4]) * sb.x + bf2f((unsigned short)v[5]) * sb.y +
           bf2f((unsigned short)v[6]) * sb.z + bf2f((unsigned short)v[7]) * sb.w;
  }
#pragma unroll
  for (int m = 1; m < 64; m <<= 1) dot += __shfl_xor(dot, m);
  if (lane == 0) {
    float mv[8], zv[8], svv[8];
    float M = -1e30f;
#pragma unroll
    for (int c = 0; c < 8; ++c) {
      mv[c] = pm[(size_t)c * 8192 + row];
      zv[c] = pz[(size_t)c * 8192 + row];
      svv[c] = ps[(size_t)c * 8192 + row];
      M = fmaxf(M, mv[c]);
    }
    float Z = 0.f, S = 0.f;
#pragma unroll
    for (int c = 0; c < 8; ++c) {
      float e = expf(mv[c] - M);
      Z += zv[c] * e;
      S += e * (svv[c] + (mv[c] - M) * zv[c]);
    }
    float loss = S / Z - logf(Z);
    out[row] = loss * dot * rnorm[row] * (1.f / 8192.f);
  }
}

// ---------------------------------------------------------------------------
extern "C" void kernel_launch(void* const* d_in, const int* in_sizes, int n_in,
                              void* d_out, int out_size, void* d_ws, size_t ws_size,
                              hipStream_t stream) {
  (void)in_sizes; (void)n_in; (void)out_size; (void)ws_size;
  const float* x = (const float*)d_in[0];
  const float* W = (const float*)d_in[1];
  const float* b = (const float*)d_in[2];
  float* out = (float*)d_out;
  char* ws = (char*)d_ws;

  // ws layout (bytes):
  unsigned short* Wt = (unsigned short*)(ws + 0);           // 2 MiB
  unsigned short* xbf = (unsigned short*)(ws + 2097152);    // 16 MiB
  float* rnorm = (float*)(ws + 18874368);                   // 32 KiB
  float* s = (float*)(ws + 18907136);                       // 4 KiB
  float* pm = (float*)(ws + 18911232);                      // 8*8192*4 = 256 KiB
  float* pz = (float*)(ws + 18911232 + 262144);
  float* ps = (float*)(ws + 18911232 + 524288);

  hipMemsetAsync(s, 0, 4096, stream);
  k01_prep<<<768, 256, 0, stream>>>(W, Wt, x, xbf, rnorm, s);
  k3_gemm<<<512, 256, 0, stream>>>(xbf, Wt, b, pm, pz, ps);
  k4_final<<<2048, 256, 0, stream>>>(xbf, s, rnorm, pm, pz, ps, out);
}

// Round 3
// 64.383 us; speedup vs baseline: 1.1654x; 1.0464x over previous
//
#include <hip/hip_runtime.h>
#include <hip/hip_bf16.h>
#include <cstdint>
#include <cstddef>

typedef __attribute__((ext_vector_type(8))) short bf16x8;
typedef __attribute__((ext_vector_type(4))) float f32x4;

__device__ __forceinline__ unsigned short f2bf(float f) {
  union { float f; unsigned u; } v; v.f = f;
  unsigned r = v.u + 0x7FFFu + ((v.u >> 16) & 1u);
  return (unsigned short)(r >> 16);
}

__device__ __forceinline__ float bf2f(unsigned short h) {
  union { float f; unsigned u; } c; c.u = ((unsigned)h) << 16;
  return c.f;
}

__device__ __forceinline__ void gload_lds16(const void* g, void* l) {
  __builtin_amdgcn_global_load_lds(
      (const __attribute__((address_space(1))) unsigned int*)g,
      (__attribute__((address_space(3))) unsigned int*)l, 16, 0, 0);
}

// ---------------------------------------------------------------------------
// K01 fused: blocks [0,256): W transpose->bf16 Wt[1024cls][1024k] (pad 0).
//            blocks [256,768): per-row rnorm, x->bf16, s += xn (atomics).
// ---------------------------------------------------------------------------
__global__ __launch_bounds__(256) void k01_prep(const float* __restrict__ W,
                                                unsigned short* __restrict__ Wt,
                                                const float* __restrict__ x,
                                                unsigned short* __restrict__ xbf,
                                                float* __restrict__ rnorm,
                                                float* __restrict__ s) {
  __shared__ __align__(16) char sm[16640];
  int tid = threadIdx.x;
  if (blockIdx.x < 256) {
    float (*tile)[65] = (float(*)[65])sm;
    int k0 = (blockIdx.x & 15) * 64;
    int c0 = (blockIdx.x >> 4) * 64;
    int tx = tid & 63;
    int ty = tid >> 6;
#pragma unroll
    for (int i = 0; i < 16; ++i) {
      int r = i * 4 + ty;
      int c = c0 + tx;
      tile[r][tx] = (c < 1000) ? W[(size_t)(k0 + r) * 1000 + c] : 0.f;
    }
    __syncthreads();
#pragma unroll
    for (int i = 0; i < 16; ++i) {
      int ct = i * 4 + ty;
      Wt[(size_t)(c0 + ct) * 1024 + (k0 + tx)] = f2bf(tile[tx][ct]);
    }
    return;
  }
  float (*sblk)[1024] = (float(*)[1024])sm;
  int bid = blockIdx.x - 256;
  int wid = tid >> 6, lane = tid & 63;
  float4 sacc[4];
#pragma unroll
  for (int j = 0; j < 4; ++j) sacc[j] = make_float4(0.f, 0.f, 0.f, 0.f);
#pragma unroll
  for (int r = 0; r < 4; ++r) {
    int row = bid * 16 + wid * 4 + r;
    const float4* xr = (const float4*)(x + (size_t)row * 1024);
    float4 v[4];
    float ss = 0.f;
#pragma unroll
    for (int j = 0; j < 4; ++j) {
      v[j] = xr[lane + j * 64];
      ss += v[j].x * v[j].x + v[j].y * v[j].y + v[j].z * v[j].z + v[j].w * v[j].w;
    }
#pragma unroll
    for (int m = 1; m < 64; m <<= 1) ss += __shfl_xor(ss, m);
    float rn = 1.f / fmaxf(sqrtf(ss), 1e-8f);
    if (lane == 0) rnorm[row] = rn;
#pragma unroll
    for (int j = 0; j < 4; ++j) {
      ushort4 hv;
      hv.x = f2bf(v[j].x); hv.y = f2bf(v[j].y);
      hv.z = f2bf(v[j].z); hv.w = f2bf(v[j].w);
      ((ushort4*)(xbf + (size_t)row * 1024))[lane + j * 64] = hv;
      sacc[j].x += v[j].x * rn; sacc[j].y += v[j].y * rn;
      sacc[j].z += v[j].z * rn; sacc[j].w += v[j].w * rn;
    }
  }
#pragma unroll
  for (int j = 0; j < 4; ++j) ((float4*)sblk[wid])[j * 64 + lane] = sacc[j];
  __syncthreads();
  for (int d = tid; d < 1024; d += 256) {
    float t = sblk[0][d] + sblk[1][d] + sblk[2][d] + sblk[3][d];
    atomicAdd(&s[d], t);
  }
}

// ---------------------------------------------------------------------------
// K3: bf16 MFMA GEMM (cls x rows) + fused softmax partials.
// T2+T3+T4+T5 schedule: block = 128 cls x 256 rows, BK=64, 16 K-tiles.
// Grid 256 = 8 cls-chunks (XCD-aligned) x 32 row-blocks, 512 thr (8 waves,
// 2c x 4r, per-wave 64x64). Tri-buffered LDS (3 x 48KB), depth-2 prefetch:
// iter t stages tile t+2; top-of-iter s_waitcnt vmcnt(6) (tile t ready,
// tile t+1's 6 loads stay in flight across the barrier), ONE s_barrier/iter.
// LDS XOR-swizzle: linear gload_lds dest + inverse-swizzled global source
// (((l&7)^(l>>3))<<4) + swizzled reads (kb ^ ((row&7)<<4)) -> conflict-free.
// ---------------------------------------------------------------------------
#define LDSBUF 49152

__global__ __launch_bounds__(512) void k3_gemm(const unsigned short* __restrict__ xbf,
                                               const unsigned short* __restrict__ wt,
                                               const float* __restrict__ bias,
                                               float* __restrict__ pm,
                                               float* __restrict__ pz,
                                               float* __restrict__ ps) {
  __shared__ __align__(16) char lds[147456];  // 3 bufs x (A 16KB + B 32KB)

  int tid = threadIdx.x;
  int lane = tid & 63;
  int wid = tid >> 6;
  int wc = wid & 1;   // cls half (64)
  int wr = wid >> 1;  // row quarter (64)
  int cb = blockIdx.x & 7;   // cls chunk -> XCD (i%8 round-robin)
  int rb = blockIdx.x >> 3;  // 0..31
  int C0 = cb * 128;
  int R0 = rb * 256;

  // bias (+pad mask) folded into acc init. C/D map: row(cls)=(lane>>4)*4+q,
  // col(xrow)=lane&15.
  float bv[4][4];
#pragma unroll
  for (int mf = 0; mf < 4; ++mf)
#pragma unroll
    for (int q = 0; q < 4; ++q) {
      int cls_g = C0 + wc * 64 + mf * 16 + (lane >> 4) * 4 + q;
      bv[mf][q] = (cls_g < 1000) ? bias[cls_g] : -1e30f;
    }
  f32x4 acc[4][4];
#pragma unroll
  for (int mf = 0; mf < 4; ++mf)
#pragma unroll
    for (int nf = 0; nf < 4; ++nf)
#pragma unroll
      for (int q = 0; q < 4; ++q) acc[mf][nf][q] = bv[mf][q];

  const char* gA = (const char*)(wt + (size_t)C0 * 1024);
  const char* gB = (const char*)(xbf + (size_t)R0 * 1024);
  int grow = lane >> 3;                         // row within 8-row wave chunk
  int gswz = ((lane & 7) ^ grow) << 4;          // inverse-swizzled k-byte src

  // stage one 8KB round: rows r*64+wid*8..+7, linear LDS dest (wave-uniform).
#define STA(kt, b, r)                                                          \
  gload_lds16(gA + (size_t)((r) * 64 + wid * 8 + grow) * 2048 + (kt) * 128 +   \
                  gswz,                                                        \
              lds + (b) * LDSBUF + (r) * 8192 + wid * 1024)
#define STB(kt, b, r)                                                          \
  gload_lds16(gB + (size_t)((r) * 64 + wid * 8 + grow) * 2048 + (kt) * 128 +   \
                  gswz,                                                        \
              lds + (b) * LDSBUF + 16384 + (r) * 8192 + wid * 1024)

  // prologue: tiles 0 and 1 (oldest-first for vmcnt counting)
  STA(0, 0, 0); STA(0, 0, 1); STB(0, 0, 0); STB(0, 0, 1); STB(0, 0, 2); STB(0, 0, 3);
  STA(1, 1, 0); STA(1, 1, 1); STB(1, 1, 0); STB(1, 1, 1); STB(1, 1, 2); STB(1, 1, 3);

  int rsw = (lane & 7) << 4;  // read-side swizzle (row&7 == lane&7 for frags)
  int kcol = (lane >> 4) * 16;

  for (int t = 0; t < 16; ++t) {
    asm volatile("s_waitcnt vmcnt(6)" ::: "memory");
    __builtin_amdgcn_s_barrier();
    asm volatile("" ::: "memory");
    const char* A = lds + (t % 3) * LDSBUF;
    const char* B = A + 16384;
    int nt = t + 2;
    int nb = nt % 3;
    bool pf = nt < 16;

    // P0: stage A(t+2), read all a-frags + b(nf=0), MFMA nf=0
    if (pf) { STA(nt, nb, 0); STA(nt, nb, 1); }
    bf16x8 a[4][2];
#pragma unroll
    for (int mf = 0; mf < 4; ++mf)
#pragma unroll
      for (int ks = 0; ks < 2; ++ks)
        a[mf][ks] = *(const bf16x8*)(A + (wc * 64 + mf * 16 + (lane & 15)) * 128 +
                                     ((ks * 64 + kcol) ^ rsw));
    {
      bf16x8 b0[2];
#pragma unroll
      for (int ks = 0; ks < 2; ++ks)
        b0[ks] = *(const bf16x8*)(B + (wr * 64 + 0 * 16 + (lane & 15)) * 128 +
                                  ((ks * 64 + kcol) ^ rsw));
      __builtin_amdgcn_s_setprio(1);
#pragma unroll
      for (int ks = 0; ks < 2; ++ks)
#pragma unroll
        for (int mf = 0; mf < 4; ++mf)
          acc[mf][0] = __builtin_amdgcn_mfma_f32_16x16x32_bf16(a[mf][ks], b0[ks],
                                                               acc[mf][0], 0, 0, 0);
      __builtin_amdgcn_s_setprio(0);
    }
    // P1
    if (pf) { STB(nt, nb, 0); STB(nt, nb, 1); }
    {
      bf16x8 b1[2];
#pragma unroll
      for (int ks = 0; ks < 2; ++ks)
        b1[ks] = *(const bf16x8*)(B + (wr * 64 + 1 * 16 + (lane & 15)) * 128 +
                                  ((ks * 64 + kcol) ^ rsw));
      __builtin_amdgcn_s_setprio(1);
#pragma unroll
      for (int ks = 0; ks < 2; ++ks)
#pragma unroll
        for (int mf = 0; mf < 4; ++mf)
          acc[mf][1] = __builtin_amdgcn_mfma_f32_16x16x32_bf16(a[mf][ks], b1[ks],
                                                               acc[mf][1], 0, 0, 0);
      __builtin_amdgcn_s_setprio(0);
    }
    // P2
    if (pf) { STB(nt, nb, 2); STB(nt, nb, 3); }
    {
      bf16x8 b2[2];
#pragma unroll
      for (int ks = 0; ks < 2; ++ks)
        b2[ks] = *(const bf16x8*)(B + (wr * 64 + 2 * 16 + (lane & 15)) * 128 +
                                  ((ks * 64 + kcol) ^ rsw));
      __builtin_amdgcn_s_setprio(1);
#pragma unroll
      for (int ks = 0; ks < 2; ++ks)
#pragma unroll
        for (int mf = 0; mf < 4; ++mf)
          acc[mf][2] = __builtin_amdgcn_mfma_f32_16x16x32_bf16(a[mf][ks], b2[ks],
                                                               acc[mf][2], 0, 0, 0);
      __builtin_amdgcn_s_setprio(0);
    }
    // P3
    {
      bf16x8 b3[2];
#pragma unroll
      for (int ks = 0; ks < 2; ++ks)
        b3[ks] = *(const bf16x8*)(B + (wr * 64 + 3 * 16 + (lane & 15)) * 128 +
                                  ((ks * 64 + kcol) ^ rsw));
      __builtin_amdgcn_s_setprio(1);
#pragma unroll
      for (int ks = 0; ks < 2; ++ks)
#pragma unroll
        for (int mf = 0; mf < 4; ++mf)
          acc[mf][3] = __builtin_amdgcn_mfma_f32_16x16x32_bf16(a[mf][ks], b3[ks],
                                                               acc[mf][3], 0, 0, 0);
      __builtin_amdgcn_s_setprio(0);
    }
  }

  // Epilogue: per x-row softmax stats over this wave's 64 cls; merge the two
  // cls-halves (wc) via LDS (safe after full sync).
  __syncthreads();
  float* mm = (float*)lds;
  float* zz = mm + 512;
  float* sv = zz + 512;
#pragma unroll
  for (int nf = 0; nf < 4; ++nf) {
    float m1 = -1e30f;
#pragma unroll
    for (int mf = 0; mf < 4; ++mf)
#pragma unroll
      for (int q = 0; q < 4; ++q) m1 = fmaxf(m1, acc[mf][nf][q]);
    m1 = fmaxf(m1, __shfl_xor(m1, 16));
    m1 = fmaxf(m1, __shfl_xor(m1, 32));
    float z1 = 0.f, s1 = 0.f;
#pragma unroll
    for (int mf = 0; mf < 4; ++mf)
#pragma unroll
      for (int q = 0; q < 4; ++q) {
        float tt = acc[mf][nf][q] - m1;
        float e = expf(tt);
        z1 += e;
        s1 += e * tt;
      }
    z1 += __shfl_xor(z1, 16); z1 += __shfl_xor(z1, 32);
    s1 += __shfl_xor(s1, 16); s1 += __shfl_xor(s1, 32);
    if (lane < 16) {
      int r = wr * 64 + nf * 16 + lane;
      mm[wc * 256 + r] = m1;
      zz[wc * 256 + r] = z1;
      sv[wc * 256 + r] = s1;
    }
  }
  __syncthreads();
  if (tid < 256) {
    float m0 = mm[tid], mA = mm[256 + tid];
    float z0 = zz[tid], zA = zz[256 + tid];
    float s0 = sv[tid], sA = sv[256 + tid];
    float M = fmaxf(m0, mA);
    float e0 = expf(m0 - M), e1 = expf(mA - M);
    float Z = z0 * e0 + zA * e1;
    float S = e0 * (s0 + (m0 - M) * z0) + e1 * (sA + (mA - M) * zA);
    size_t o = (size_t)cb * 8192 + R0 + tid;
    pm[o] = M;
    pz[o] = Z;
    ps[o] = S;
  }
}

// ---------------------------------------------------------------------------
// K4: merge 8 chunk-partials -> loss; weight = dot(xbf_row, s)*rnorm/B.
// ---------------------------------------------------------------------------
__global__ __launch_bounds__(256) void k4_final(const unsigned short* __restrict__ xbf,
                                                const float* __restrict__ s,
                                                const float* __restrict__ rnorm,
                                                const float* __restrict__ pm,
                                                const float* __restrict__ pz,
                                                const float* __restrict__ ps,
                                                float* __restrict__ out) {
  int tid = threadIdx.x;
  int wid = tid >> 6, lane = tid & 63;
  int row = blockIdx.x * 4 + wid;
  const bf16x8* xr = (const bf16x8*)(xbf + (size_t)row * 1024);
  const float4* s4 = (const float4*)s;
  float dot = 0.f;
#pragma unroll
  for (int j = 0; j < 2; ++j) {
    bf16x8 v = xr[lane + j * 64];
    float4 sa = s4[(lane + j * 64) * 2];
    float4 sb = s4[(lane + j * 64) * 2 + 1];
    dot += bf2f((unsigned short)v[0]) * sa.x + bf2f((unsigned short)v[1]) * sa.y +
           bf2f((unsigned short)v[2]) * sa.z + bf2f((unsigned short)v[3]) * sa.w +
           bf2f((unsigned short)v[4]) * sb.x + bf2f((unsigned short)v[5]) * sb.y +
           bf2f((unsigned short)v[6]) * sb.z + bf2f((unsigned short)v[7]) * sb.w;
  }
#pragma unroll
  for (int m = 1; m < 64; m <<= 1) dot += __shfl_xor(dot, m);
  if (lane == 0) {
    float mv[8], zv[8], svv[8];
    float M = -1e30f;
#pragma unroll
    for (int c = 0; c < 8; ++c) {
      mv[c] = pm[(size_t)c * 8192 + row];
      zv[c] = pz[(size_t)c * 8192 + row];
      svv[c] = ps[(size_t)c * 8192 + row];
      M = fmaxf(M, mv[c]);
    }
    float Z = 0.f, S = 0.f;
#pragma unroll
    for (int c = 0; c < 8; ++c) {
      float e = expf(mv[c] - M);
      Z += zv[c] * e;
      S += e * (svv[c] + (mv[c] - M) * zv[c]);
    }
    float loss = S / Z - logf(Z);
    out[row] = loss * dot * rnorm[row] * (1.f / 8192.f);
  }
}

// ---------------------------------------------------------------------------
extern "C" void kernel_launch(void* const* d_in, const int* in_sizes, int n_in,
                              void* d_out, int out_size, void* d_ws, size_t ws_size,
                              hipStream_t stream) {
  (void)in_sizes; (void)n_in; (void)out_size; (void)ws_size;
  const float* x = (const float*)d_in[0];
  const float* W = (const float*)d_in[1];
  const float* b = (const float*)d_in[2];
  float* out = (float*)d_out;
  char* ws = (char*)d_ws;

  unsigned short* Wt = (unsigned short*)(ws + 0);           // 2 MiB
  unsigned short* xbf = (unsigned short*)(ws + 2097152);    // 16 MiB
  float* rnorm = (float*)(ws + 18874368);                   // 32 KiB
  float* s = (float*)(ws + 18907136);                       // 4 KiB
  float* pm = (float*)(ws + 18911232);                      // 8*8192*4 = 256 KiB
  float* pz = (float*)(ws + 18911232 + 262144);
  float* ps = (float*)(ws + 18911232 + 524288);

  hipMemsetAsync(s, 0, 4096, stream);
  k01_prep<<<768, 256, 0, stream>>>(W, Wt, x, xbf, rnorm, s);
  k3_gemm<<<256, 512, 0, stream>>>(xbf, Wt, b, pm, pz, ps);
  k4_final<<<2048, 256, 0, stream>>>(xbf, s, rnorm, pm, pz, ps, out);
}